// Round 11
// baseline (163.432 us; speedup 1.0000x reference)
//
#include <hip/hip_runtime.h>
#include <hip/hip_bf16.h>

// RPN head: conv3x3(512->512)+ReLU, then 1x1 cls(18)+2-way softmax and 1x1 bbox(36).
// R11: FUSED conv+heads. Conv block = 512co x 128pos (BK=32, 8 waves 4Mx2N, per-wave
// tile 128x64 unchanged), dbuf 80KB LDS, R4-style 2-phase K-loop (288 tiles->144).
// Epilogue: rc staged to LDS [128pos][512ci] (XOR-swizzled), heads GEMM in-kernel
// (A = fragment-packed WhbF, coalesced 1KB streams), fused softmax-pair + bias.
// Eliminates rc2 HBM write+read (62 MB) and the heads kernel launch.

typedef __bf16 bf16_t;
typedef __attribute__((ext_vector_type(8))) __bf16 bf16x8;
typedef __attribute__((ext_vector_type(4))) __bf16 bf16x4;
typedef __attribute__((ext_vector_type(4))) float f32x4;

#define HW 3800
#define XP_IMG (52 * 78 * 512)

__device__ __forceinline__ void gload_lds16(const bf16_t* g, char* l) {
  __builtin_amdgcn_global_load_lds(
      (const __attribute__((address_space(1))) unsigned int*)g,
      (__attribute__((address_space(3))) unsigned int*)l, 16, 0, 0);
}

// Merged prep: blocks 0..1599 pad-transpose, 1600..1615 halo-zero,
// 1616..2127 wtrans, 2128..2143 WhbF fragment-pack.
__global__ __launch_bounds__(256) void prep_all(const float* __restrict__ x,
                                                const float* __restrict__ cw,
                                                const float* __restrict__ clsw,
                                                const float* __restrict__ boxw,
                                                bf16_t* __restrict__ Xp,
                                                bf16_t* __restrict__ Wt,
                                                bf16_t* __restrict__ WhbF) {
  __shared__ __align__(16) bf16_t tile[76][136];
  __shared__ bf16_t lw[4608];
  const int t = threadIdx.x;
  const int blk = blockIdx.x;
  if (blk < 1600) {
    const int cb = blk & 3;
    int r = blk >> 2;
    const int h = r % 50, b = r / 50;
#pragma unroll
    for (int it = 0; it < 10; ++it) {
      int idx = it * 256 + t;
      if (idx < 2432) {
        int c = idx / 19, w4 = idx - c * 19;
        const float4 v = *(const float4*)(x +
            (((size_t)(b * 512 + cb * 128 + c)) * 50 + h) * 76 + w4 * 4);
        tile[w4 * 4 + 0][c] = (bf16_t)v.x;
        tile[w4 * 4 + 1][c] = (bf16_t)v.y;
        tile[w4 * 4 + 2][c] = (bf16_t)v.z;
        tile[w4 * 4 + 3][c] = (bf16_t)v.w;
      }
    }
    __syncthreads();
#pragma unroll
    for (int it = 0; it < 5; ++it) {
      int idx = it * 256 + t;
      if (idx < 1216) {
        int w = idx >> 4, c8 = idx & 15;
        bf16x8 v = *(const bf16x8*)&tile[w][c8 * 8];
        *(bf16x8*)(Xp + ((size_t)(b * 52 + h + 1) * 78 + (w + 1)) * 512 +
                   cb * 128 + c8 * 8) = v;
      }
    }
  } else if (blk < 1616) {
    const int blk2 = blk - 1600;
    const int b = blk2 >> 1, half = blk2 & 1;
    bf16x8 z;
#pragma unroll
    for (int j = 0; j < 8; ++j) z[j] = (bf16_t)0.f;
#pragma unroll
    for (int it = 0; it < 32; ++it) {
      int idx = it * 256 + t;
      int q = half * 128 + (idx >> 6);
      int c8 = idx & 63;
      int h, w;
      if (q < 78)       { h = 0;           w = q; }
      else if (q < 156) { h = 51;          w = q - 78; }
      else if (q < 206) { h = q - 156 + 1; w = 0; }
      else              { h = q - 206 + 1; w = 77; }
      *(bf16x8*)(Xp + ((size_t)(b * 52 + h) * 78 + w) * 512 + c8 * 8) = z;
    }
  } else if (blk < 2128) {
    const int co = blk - 1616;
    const float* src = cw + (size_t)co * 4608;
#pragma unroll
    for (int it = 0; it < 18; ++it) {
      int idx = it * 256 + t;
      lw[idx] = (bf16_t)src[idx];
    }
    __syncthreads();
#pragma unroll
    for (int s = 0; s < 9; ++s) {
      int ci = t * 2;
      bf16_t v0 = lw[ci * 9 + s], v1 = lw[(ci + 1) * 9 + s];
      bf16_t* dst = Wt + ((size_t)s * 512 + co) * 512 + ci;
      dst[0] = v0; dst[1] = v1;
    }
  } else {
    // WhbF fragment-pack: slot idx = mf*1024 + kt*64 + lane; each slot = 8 bf16.
    // Lane holds A-frag elems: co2row = mf*16 + (lane&15), ci = kt*32+(lane>>4)*8+j.
    // Row permutation: row 2a = cls logit0 ch a, 2a+1 = logit1 ch a; 18..53 bbox.
    int idx = (blk - 2128) * 256 + t;      // 0..4095
    int lane = idx & 63, kt = (idx >> 6) & 15, mf = idx >> 10;
    int row = mf * 16 + (lane & 15);
    int ci0 = kt * 32 + (lane >> 4) * 8;
    bf16x8 v;
#pragma unroll
    for (int j = 0; j < 8; ++j) {
      float val = 0.f;
      if (row < 18) {
        int a = row >> 1, logit = row & 1;
        val = clsw[(logit * 9 + a) * 512 + ci0 + j];
      } else if (row < 54) {
        val = boxw[(row - 18) * 512 + ci0 + j];
      }
      v[j] = (bf16_t)val;
    }
    *(bf16x8*)(WhbF + (size_t)idx * 8) = v;
  }
}

// Fused conv3x3 + heads: 512co x 128pos tile, BK=32, 8 waves (4Mx2N), dbuf 80KB.
__global__ __launch_bounds__(512) void conv_fused(const bf16_t* __restrict__ Xp,
                                                  const bf16_t* __restrict__ Wt,
                                                  const float* __restrict__ convb,
                                                  const bf16_t* __restrict__ WhbF,
                                                  const float* __restrict__ clsb,
                                                  const float* __restrict__ boxb,
                                                  float* __restrict__ out) {
  // K-loop: buf q at q*40960: A[512 rows][64B] = 32KB, B[128 rows][64B] at +32768.
  // Epilogue: whole smem = rc_lds[128 pos][1024B] (128KB).
  __shared__ __align__(16) char smem[131072];
  const int tid = threadIdx.x;
  const int lane = tid & 63;
  const int wv = tid >> 6;          // 0..7
  const int wm = wv >> 1;           // 0..3  (co quarter: 128 rows)
  const int wn = wv & 1;            // 0..1  (pos half: 64)
  const int lm = lane & 15, lg = lane >> 4;

  // XCD swizzle: 240 blocks, one image per XCD
  const int raw = blockIdx.x;
  const int wg = (raw & 7) * 30 + (raw >> 3);
  const int b = wg / 30;
  const int pos_base = (wg - b * 30) * 128;
  const bf16_t* XpB = Xp + (size_t)b * XP_IMG;

  // staging descriptors (BK=32: 64B rows, 4 chunks; swizzle c = p ^ ((r>>1)&3))
  int aSrc[4], aDst[4];
#pragma unroll
  for (int i = 0; i < 4; ++i) {
    int d = i * 512 + tid;
    int r = d >> 2, p = d & 3, c = p ^ ((r >> 1) & 3);
    aSrc[i] = r * 512 + c * 8;
    aDst[i] = r * 64 + p * 16;
  }
  int bSpa, bCc, bDst;
  {
    int r = tid >> 2, p = tid & 3, c = p ^ ((r >> 1) & 3);
    int m = pos_base + r; if (m > HW - 1) m = HW - 1;    // tail clamp
    bSpa = (m / 76) * 78 + (m - (m / 76) * 76);
    bCc = c * 8;
    bDst = 32768 + r * 64 + p * 16;
  }

  // fragment read offsets: addr = buf + row*64 + koff, koff = (lg^((lm>>1)&3))<<4
  const int koff = (lg ^ ((lm >> 1) & 3)) << 4;
  int aOff[8], bOff[4];
#pragma unroll
  for (int m = 0; m < 8; ++m) aOff[m] = (wm * 128 + m * 16 + lm) * 64 + koff;
#pragma unroll
  for (int n = 0; n < 4; ++n) bOff[n] = 32768 + (wn * 64 + n * 16 + lm) * 64 + koff;

  f32x4 acc[8][4];
#pragma unroll
  for (int i = 0; i < 8; ++i)
#pragma unroll
    for (int j = 0; j < 4; ++j) acc[i][j] = (f32x4){0.f, 0.f, 0.f, 0.f};

#define STAGE_A(KT, BUF) {                                                      \
    const int s_ = (KT) >> 4, cb_ = (KT) & 15;                                  \
    const bf16_t* p_ = Wt + (size_t)s_ * 262144 + cb_ * 32;                     \
    _Pragma("unroll")                                                           \
    for (int i_ = 0; i_ < 4; ++i_)                                              \
      gload_lds16(p_ + aSrc[i_], (BUF) + aDst[i_]);                             \
  }
#define STAGE_B(KT, BUF) {                                                      \
    const int s_ = (KT) >> 4, cb_ = (KT) & 15;                                  \
    const int sp_ = (s_ / 3) * 78 + (s_ - (s_ / 3) * 3);                        \
    gload_lds16(XpB + (size_t)(bSpa + sp_) * 512 + bCc + cb_ * 32,              \
                (BUF) + bDst);                                                  \
  }

  // prologue: stage tile 0 into buf0
  STAGE_A(0, smem)
  STAGE_B(0, smem)
  asm volatile("s_waitcnt vmcnt(0)" ::: "memory");
  __builtin_amdgcn_s_barrier();
  __builtin_amdgcn_sched_barrier(0);

  for (int kt = 0; kt < 144; ++kt) {          // K-tile = (s = kt>>4, cb = kt&15)
    const char* Ab = smem + (kt & 1) * 40960;
    char* Anxt = smem + ((kt + 1) & 1) * 40960;
    const int tn = kt + 1;
    bf16x8 pa[4], pb[4];

    // ---- phase 0: issue A-stage(t+1); read B + A_lo; MFMA m0-3
    if (tn < 144) STAGE_A(tn, Anxt)
#pragma unroll
    for (int n = 0; n < 4; ++n) pb[n] = *(const bf16x8*)(Ab + bOff[n]);
#pragma unroll
    for (int f = 0; f < 4; ++f) pa[f] = *(const bf16x8*)(Ab + aOff[f]);
    __builtin_amdgcn_s_setprio(1);
#pragma unroll
    for (int f = 0; f < 4; ++f)
#pragma unroll
      for (int n = 0; n < 4; ++n)
        acc[f][n] = __builtin_amdgcn_mfma_f32_16x16x32_bf16(pa[f], pb[n], acc[f][n], 0, 0, 0);
    __builtin_amdgcn_s_setprio(0);
    __builtin_amdgcn_s_barrier();

    // ---- phase 1: issue B-stage(t+1); read A_hi; MFMA m4-7 (pb held)
    if (tn < 144) STAGE_B(tn, Anxt)
#pragma unroll
    for (int f = 0; f < 4; ++f) pa[f] = *(const bf16x8*)(Ab + aOff[4 + f]);
    __builtin_amdgcn_s_setprio(1);
#pragma unroll
    for (int f = 0; f < 4; ++f)
#pragma unroll
      for (int n = 0; n < 4; ++n)
        acc[4 + f][n] = __builtin_amdgcn_mfma_f32_16x16x32_bf16(pa[f], pb[n], acc[4 + f][n], 0, 0, 0);
    __builtin_amdgcn_s_setprio(0);

    asm volatile("s_waitcnt vmcnt(0)" ::: "memory");
    __builtin_amdgcn_s_barrier();
    __builtin_amdgcn_sched_barrier(0);
  }
#undef STAGE_A
#undef STAGE_B

  // ---- epilogue 1: bias + ReLU, stage rc into LDS [128 pos][1024B], swizzled:
  // byte = pos*1024 + ((co*2) ^ ((pos&7)<<4))
#pragma unroll
  for (int m = 0; m < 8; ++m) {
    const int co = wm * 128 + m * 16 + lg * 4;
    const float4 bias = *(const float4*)(convb + co);
    const int cb2 = co * 2;
#pragma unroll
    for (int n = 0; n < 4; ++n) {
      const int pl = wn * 64 + n * 16 + lm;
      bf16x4 v;
      float z0 = acc[m][n][0] + bias.x; v[0] = (bf16_t)(z0 > 0.f ? z0 : 0.f);
      float z1 = acc[m][n][1] + bias.y; v[1] = (bf16_t)(z1 > 0.f ? z1 : 0.f);
      float z2 = acc[m][n][2] + bias.z; v[2] = (bf16_t)(z2 > 0.f ? z2 : 0.f);
      float z3 = acc[m][n][3] + bias.w; v[3] = (bf16_t)(z3 > 0.f ? z3 : 0.f);
      *(bf16x4*)(smem + pl * 1024 + (cb2 ^ ((pl & 7) << 4))) = v;
    }
  }
  __syncthreads();

  // ---- epilogue 2: heads GEMM. Wave wv: C[64 co2][16 pos], pos seg = wv*16.
  // A-frag: WhbF slot (mf*16+kt)*64+lane (coalesced). B-frag: rc_lds row ps+lm.
  {
    const int ps = wv * 16;
    const int prow = ps + lm;
    const int rsw = (lm & 7) << 4;
    f32x4 acc2[4];
#pragma unroll
    for (int i = 0; i < 4; ++i) acc2[i] = (f32x4){0.f, 0.f, 0.f, 0.f};
#pragma unroll
    for (int kt = 0; kt < 16; ++kt) {
      const bf16x8 bfr = *(const bf16x8*)(smem + prow * 1024 +
                                          ((kt * 64 + lg * 16) ^ rsw));
#pragma unroll
      for (int mf = 0; mf < 4; ++mf) {
        const bf16x8 af = *(const bf16x8*)(WhbF +
            ((size_t)(mf * 16 + kt) * 64 + lane) * 8);
        acc2[mf] = __builtin_amdgcn_mfma_f32_16x16x32_bf16(af, bfr, acc2[mf], 0, 0, 0);
      }
    }
    const int pos = pos_base + ps + lm;
    if (pos < HW) {
      float* boxOut = out + (size_t)8 * 18 * HW;
#pragma unroll
      for (int mf = 0; mf < 4; ++mf) {
#pragma unroll
        for (int pr = 0; pr < 2; ++pr) {
          const int row0 = mf * 16 + lg * 4 + pr * 2;
          const float v0 = acc2[mf][pr * 2];
          const float v1 = acc2[mf][pr * 2 + 1];
          if (row0 < 18) {
            const int a = row0 >> 1;
            const float s0 = v0 + clsb[a];
            const float s1 = v1 + clsb[9 + a];
            const float mx = fmaxf(s0, s1);
            const float e0 = expf(s0 - mx), e1 = expf(s1 - mx);
            const float inv = 1.0f / (e0 + e1);
            out[((size_t)(b * 18 + a)) * HW + pos] = e0 * inv;
            out[((size_t)(b * 18 + 9 + a)) * HW + pos] = e1 * inv;
          } else if (row0 < 54) {
            const int c0 = row0 - 18;
            boxOut[((size_t)(b * 36 + c0)) * HW + pos] = v0 + boxb[c0];
            boxOut[((size_t)(b * 36 + c0 + 1)) * HW + pos] = v1 + boxb[c0 + 1];
          }
        }
      }
    }
  }
}

extern "C" void kernel_launch(void* const* d_in, const int* in_sizes, int n_in,
                              void* d_out, int out_size, void* d_ws, size_t ws_size,
                              hipStream_t stream) {
  (void)in_sizes; (void)n_in; (void)out_size; (void)ws_size;
  const float* base_feat = (const float*)d_in[0];
  const float* conv_w = (const float*)d_in[4];
  const float* conv_b = (const float*)d_in[5];
  const float* cls_w  = (const float*)d_in[6];
  const float* cls_b  = (const float*)d_in[7];
  const float* bbox_w = (const float*)d_in[8];
  const float* bbox_b = (const float*)d_in[9];

  char* ws = (char*)d_ws;
  bf16_t* Xp   = (bf16_t*)(ws);                // 8*52*78*512*2 = 33,226,752 B
  bf16_t* Wt   = (bf16_t*)(ws + 33226752);     // 9*512*512*2   =  4,718,592 B
  bf16_t* WhbF = (bf16_t*)(ws + 37945344);     // 4*16*64*8*2   =     65,536 B

  hipLaunchKernelGGL(prep_all,   dim3(2144), dim3(256), 0, stream,
                     base_feat, conv_w, cls_w, bbox_w, Xp, Wt, WhbF);
  hipLaunchKernelGGL(conv_fused, dim3(240),  dim3(512), 0, stream,
                     Xp, Wt, conv_b, WhbF, cls_b, bbox_b, (float*)d_out);
}

// Round 12
// 150.429 us; speedup vs baseline: 1.0864x; 1.0864x over previous
//
#include <hip/hip_runtime.h>
#include <hip/hip_bf16.h>

// RPN head: conv3x3(512->512)+ReLU, then 1x1 cls(18)+2-way softmax and 1x1 bbox(36).
// R12: fused conv+heads with BK=64 restored. Conv block = 512co x 128pos, 8 waves
// (4Mx2N, per-wave 128x64), A-dbuf 2x64KB + B-dbuf 2x16KB = 160KB LDS (gfx950 max),
// R4-rate 4-phase K-loop (72 tiles, 3+boundary barriers per 64 MFMA). Epilogue:
// rc -> LDS [128pos][512ci] swizzled, in-kernel heads GEMM (WhbF fragment-packed),
// fused softmax-pair + bias. No rc2 HBM round-trip, no heads launch.

typedef __bf16 bf16_t;
typedef __attribute__((ext_vector_type(8))) __bf16 bf16x8;
typedef __attribute__((ext_vector_type(4))) __bf16 bf16x4;
typedef __attribute__((ext_vector_type(4))) float f32x4;

#define HW 3800
#define XP_IMG (52 * 78 * 512)

__device__ __forceinline__ void gload_lds16(const bf16_t* g, char* l) {
  __builtin_amdgcn_global_load_lds(
      (const __attribute__((address_space(1))) unsigned int*)g,
      (__attribute__((address_space(3))) unsigned int*)l, 16, 0, 0);
}

// Merged prep: blocks 0..1599 pad-transpose, 1600..1615 halo-zero,
// 1616..2127 wtrans, 2128..2143 WhbF fragment-pack.
__global__ __launch_bounds__(256) void prep_all(const float* __restrict__ x,
                                                const float* __restrict__ cw,
                                                const float* __restrict__ clsw,
                                                const float* __restrict__ boxw,
                                                bf16_t* __restrict__ Xp,
                                                bf16_t* __restrict__ Wt,
                                                bf16_t* __restrict__ WhbF) {
  __shared__ __align__(16) bf16_t tile[76][136];
  __shared__ bf16_t lw[4608];
  const int t = threadIdx.x;
  const int blk = blockIdx.x;
  if (blk < 1600) {
    const int cb = blk & 3;
    int r = blk >> 2;
    const int h = r % 50, b = r / 50;
#pragma unroll
    for (int it = 0; it < 10; ++it) {
      int idx = it * 256 + t;
      if (idx < 2432) {
        int c = idx / 19, w4 = idx - c * 19;
        const float4 v = *(const float4*)(x +
            (((size_t)(b * 512 + cb * 128 + c)) * 50 + h) * 76 + w4 * 4);
        tile[w4 * 4 + 0][c] = (bf16_t)v.x;
        tile[w4 * 4 + 1][c] = (bf16_t)v.y;
        tile[w4 * 4 + 2][c] = (bf16_t)v.z;
        tile[w4 * 4 + 3][c] = (bf16_t)v.w;
      }
    }
    __syncthreads();
#pragma unroll
    for (int it = 0; it < 5; ++it) {
      int idx = it * 256 + t;
      if (idx < 1216) {
        int w = idx >> 4, c8 = idx & 15;
        bf16x8 v = *(const bf16x8*)&tile[w][c8 * 8];
        *(bf16x8*)(Xp + ((size_t)(b * 52 + h + 1) * 78 + (w + 1)) * 512 +
                   cb * 128 + c8 * 8) = v;
      }
    }
  } else if (blk < 1616) {
    const int blk2 = blk - 1600;
    const int b = blk2 >> 1, half = blk2 & 1;
    bf16x8 z;
#pragma unroll
    for (int j = 0; j < 8; ++j) z[j] = (bf16_t)0.f;
#pragma unroll
    for (int it = 0; it < 32; ++it) {
      int idx = it * 256 + t;
      int q = half * 128 + (idx >> 6);
      int c8 = idx & 63;
      int h, w;
      if (q < 78)       { h = 0;           w = q; }
      else if (q < 156) { h = 51;          w = q - 78; }
      else if (q < 206) { h = q - 156 + 1; w = 0; }
      else              { h = q - 206 + 1; w = 77; }
      *(bf16x8*)(Xp + ((size_t)(b * 52 + h) * 78 + w) * 512 + c8 * 8) = z;
    }
  } else if (blk < 2128) {
    const int co = blk - 1616;
    const float* src = cw + (size_t)co * 4608;
#pragma unroll
    for (int it = 0; it < 18; ++it) {
      int idx = it * 256 + t;
      lw[idx] = (bf16_t)src[idx];
    }
    __syncthreads();
#pragma unroll
    for (int s = 0; s < 9; ++s) {
      int ci = t * 2;
      bf16_t v0 = lw[ci * 9 + s], v1 = lw[(ci + 1) * 9 + s];
      bf16_t* dst = Wt + ((size_t)s * 512 + co) * 512 + ci;
      dst[0] = v0; dst[1] = v1;
    }
  } else {
    // WhbF fragment-pack: slot idx = mf*1024 + kt*64 + lane; 8 bf16/slot.
    // Lane's A-frag: co2row = mf*16 + (lane&15), ci = kt*32 + (lane>>4)*8 + j.
    // Row perm: row 2a = cls logit0 ch a, 2a+1 = logit1 ch a; 18..53 bbox; pad 0.
    int idx = (blk - 2128) * 256 + t;      // 0..4095
    int lane = idx & 63, kt = (idx >> 6) & 15, mf = idx >> 10;
    int row = mf * 16 + (lane & 15);
    int ci0 = kt * 32 + (lane >> 4) * 8;
    bf16x8 v;
#pragma unroll
    for (int j = 0; j < 8; ++j) {
      float val = 0.f;
      if (row < 18) {
        int a = row >> 1, logit = row & 1;
        val = clsw[(logit * 9 + a) * 512 + ci0 + j];
      } else if (row < 54) {
        val = boxw[(row - 18) * 512 + ci0 + j];
      }
      v[j] = (bf16_t)val;
    }
    *(bf16x8*)(WhbF + (size_t)idx * 8) = v;
  }
}

// Fused conv3x3 + heads: 512co x 128pos, BK=64, 8 waves (4Mx2N), 160KB LDS dbuf.
__global__ __launch_bounds__(512) void conv_fused(const bf16_t* __restrict__ Xp,
                                                  const bf16_t* __restrict__ Wt,
                                                  const float* __restrict__ convb,
                                                  const bf16_t* __restrict__ WhbF,
                                                  const float* __restrict__ clsb,
                                                  const float* __restrict__ boxb,
                                                  float* __restrict__ out) {
  // buf q at q*81920: A[512 rows][128B] = 64KB, B[128 rows][128B] at +65536.
  // Epilogue reuses [0,128KB) as rc_lds[128 pos][1024B].
  __shared__ __align__(16) char smem[163840];
  const int tid = threadIdx.x;
  const int lane = tid & 63;
  const int wv = tid >> 6;          // 0..7
  const int wm = wv >> 1;           // 0..3  (co quarter: 128 rows)
  const int wn = wv & 1;            // 0..1  (pos half: 64)
  const int lm = lane & 15, lg = lane >> 4;

  // XCD swizzle: 240 blocks, one image per XCD
  const int raw = blockIdx.x;
  const int wg = (raw & 7) * 30 + (raw >> 3);
  const int b = wg / 30;
  const int pos_base = (wg - b * 30) * 128;
  const bf16_t* XpB = Xp + (size_t)b * XP_IMG;

  // staging descriptors (128B rows, 8 chunks; source swizzle c = p ^ (r&7))
  int aSrc[8], aDst[8];
#pragma unroll
  for (int i = 0; i < 8; ++i) {
    int d = i * 512 + tid;
    int r = d >> 3, p = d & 7, c = p ^ (r & 7);
    aSrc[i] = r * 512 + c * 8;
    aDst[i] = r * 128 + p * 16;
  }
  int bSpa[2], bCc[2], bDst[2];
#pragma unroll
  for (int i = 0; i < 2; ++i) {
    int d = i * 512 + tid;
    int r = d >> 3, p = d & 7, c = p ^ (r & 7);
    int m = pos_base + r; if (m > HW - 1) m = HW - 1;    // tail clamp
    bSpa[i] = (m / 76) * 78 + (m - (m / 76) * 76);
    bCc[i] = c * 8;
    bDst[i] = 65536 + r * 128 + p * 16;
  }

  // fragment read offsets (XOR chunk swizzle, conflict-free)
  int aOff[8], bOff[4], koffs[2];
#pragma unroll
  for (int m = 0; m < 8; ++m) aOff[m] = (wm * 128 + m * 16 + lm) * 128;
#pragma unroll
  for (int n = 0; n < 4; ++n) bOff[n] = 65536 + (wn * 64 + n * 16 + lm) * 128;
#pragma unroll
  for (int ks = 0; ks < 2; ++ks) koffs[ks] = ((ks * 4 + lg) ^ (lm & 7)) << 4;

  f32x4 acc[8][4];
#pragma unroll
  for (int i = 0; i < 8; ++i)
#pragma unroll
    for (int j = 0; j < 4; ++j) acc[i][j] = (f32x4){0.f, 0.f, 0.f, 0.f};

#define STAGE_A(KT, BUF, I0, I1) {                                              \
    const int s_ = (KT) >> 3, cb_ = (KT) & 7;                                   \
    const bf16_t* p_ = Wt + (size_t)s_ * 262144 + cb_ * 64;                     \
    _Pragma("unroll")                                                           \
    for (int i_ = (I0); i_ < (I1); ++i_)                                        \
      gload_lds16(p_ + aSrc[i_], (BUF) + aDst[i_]);                             \
  }
#define STAGE_B(KT, BUF) {                                                      \
    const int s_ = (KT) >> 3, cb_ = (KT) & 7;                                   \
    const int sp_ = (s_ / 3) * 78 + (s_ - (s_ / 3) * 3);                        \
    _Pragma("unroll")                                                           \
    for (int i_ = 0; i_ < 2; ++i_)                                              \
      gload_lds16(XpB + (size_t)(bSpa[i_] + sp_) * 512 + bCc[i_] + cb_ * 64,    \
                  (BUF) + bDst[i_]);                                            \
  }

  // prologue: stage tile 0 into buf0
  STAGE_A(0, smem, 0, 8)
  STAGE_B(0, smem)
  asm volatile("s_waitcnt vmcnt(0)" ::: "memory");
  __builtin_amdgcn_s_barrier();
  __builtin_amdgcn_sched_barrier(0);

  for (int kt = 0; kt < 72; ++kt) {          // K-tile = (s = kt>>3, cb = kt&7)
    const char* Ab = smem + (kt & 1) * 81920;
    char* Anxt = smem + ((kt + 1) & 1) * 81920;
    const int tn = kt + 1;
    const bool more = (tn < 72);
    bf16x8 pa[4], pb[4];

    // ---- phase 0: stage A_h0(t+1); read B(ks0)+A_lo(ks0); MFMA acc[0-3]
    if (more) STAGE_A(tn, Anxt, 0, 4)
#pragma unroll
    for (int n = 0; n < 4; ++n) pb[n] = *(const bf16x8*)(Ab + bOff[n] + koffs[0]);
#pragma unroll
    for (int f = 0; f < 4; ++f) pa[f] = *(const bf16x8*)(Ab + aOff[f] + koffs[0]);
    __builtin_amdgcn_s_setprio(1);
#pragma unroll
    for (int f = 0; f < 4; ++f)
#pragma unroll
      for (int n = 0; n < 4; ++n)
        acc[f][n] = __builtin_amdgcn_mfma_f32_16x16x32_bf16(pa[f], pb[n], acc[f][n], 0, 0, 0);
    __builtin_amdgcn_s_setprio(0);
    __builtin_amdgcn_s_barrier();

    // ---- phase 1: stage A_h1(t+1); read A_hi(ks0); MFMA acc[4-7] (pb held)
    if (more) STAGE_A(tn, Anxt, 4, 8)
#pragma unroll
    for (int f = 0; f < 4; ++f) pa[f] = *(const bf16x8*)(Ab + aOff[4 + f] + koffs[0]);
    __builtin_amdgcn_s_setprio(1);
#pragma unroll
    for (int f = 0; f < 4; ++f)
#pragma unroll
      for (int n = 0; n < 4; ++n)
        acc[4 + f][n] = __builtin_amdgcn_mfma_f32_16x16x32_bf16(pa[f], pb[n], acc[4 + f][n], 0, 0, 0);
    __builtin_amdgcn_s_setprio(0);
    __builtin_amdgcn_s_barrier();

    // ---- phase 2: stage B(t+1); read B(ks1)+A_lo(ks1); MFMA acc[0-3]
    if (more) STAGE_B(tn, Anxt)
#pragma unroll
    for (int n = 0; n < 4; ++n) pb[n] = *(const bf16x8*)(Ab + bOff[n] + koffs[1]);
#pragma unroll
    for (int f = 0; f < 4; ++f) pa[f] = *(const bf16x8*)(Ab + aOff[f] + koffs[1]);
    __builtin_amdgcn_s_setprio(1);
#pragma unroll
    for (int f = 0; f < 4; ++f)
#pragma unroll
      for (int n = 0; n < 4; ++n)
        acc[f][n] = __builtin_amdgcn_mfma_f32_16x16x32_bf16(pa[f], pb[n], acc[f][n], 0, 0, 0);
    __builtin_amdgcn_s_setprio(0);
    __builtin_amdgcn_s_barrier();

    // ---- phase 3: read A_hi(ks1); MFMA acc[4-7]
#pragma unroll
    for (int f = 0; f < 4; ++f) pa[f] = *(const bf16x8*)(Ab + aOff[4 + f] + koffs[1]);
    __builtin_amdgcn_s_setprio(1);
#pragma unroll
    for (int f = 0; f < 4; ++f)
#pragma unroll
      for (int n = 0; n < 4; ++n)
        acc[4 + f][n] = __builtin_amdgcn_mfma_f32_16x16x32_bf16(pa[f], pb[n], acc[4 + f][n], 0, 0, 0);
    __builtin_amdgcn_s_setprio(0);

    // ---- boundary: drain t+1's stage loads, all-wave visibility
    asm volatile("s_waitcnt vmcnt(0)" ::: "memory");
    __builtin_amdgcn_s_barrier();
    __builtin_amdgcn_sched_barrier(0);
  }
#undef STAGE_A
#undef STAGE_B

  // ---- epilogue 1: bias + ReLU, rc -> LDS [128 pos][1024B], swizzled:
  // byte = pos*1024 + ((co*2) ^ ((pos&7)<<4))
#pragma unroll
  for (int m = 0; m < 8; ++m) {
    const int co = wm * 128 + m * 16 + lg * 4;
    const float4 bias = *(const float4*)(convb + co);
    const int cb2 = co * 2;
#pragma unroll
    for (int n = 0; n < 4; ++n) {
      const int pl = wn * 64 + n * 16 + lm;
      bf16x4 v;
      float z0 = acc[m][n][0] + bias.x; v[0] = (bf16_t)(z0 > 0.f ? z0 : 0.f);
      float z1 = acc[m][n][1] + bias.y; v[1] = (bf16_t)(z1 > 0.f ? z1 : 0.f);
      float z2 = acc[m][n][2] + bias.z; v[2] = (bf16_t)(z2 > 0.f ? z2 : 0.f);
      float z3 = acc[m][n][3] + bias.w; v[3] = (bf16_t)(z3 > 0.f ? z3 : 0.f);
      *(bf16x4*)(smem + pl * 1024 + (cb2 ^ ((pl & 7) << 4))) = v;
    }
  }
  __syncthreads();

  // ---- epilogue 2: heads GEMM. Wave wv: C[64 co2][16 pos], pos seg = wv*16.
  {
    const int ps = wv * 16;
    const int prow = ps + lm;
    const int rsw = (lm & 7) << 4;
    f32x4 acc2[4];
#pragma unroll
    for (int i = 0; i < 4; ++i) acc2[i] = (f32x4){0.f, 0.f, 0.f, 0.f};
#pragma unroll
    for (int kt = 0; kt < 16; ++kt) {
      const bf16x8 bfr = *(const bf16x8*)(smem + prow * 1024 +
                                          ((kt * 64 + lg * 16) ^ rsw));
#pragma unroll
      for (int mf = 0; mf < 4; ++mf) {
        const bf16x8 af = *(const bf16x8*)(WhbF +
            ((size_t)(mf * 16 + kt) * 64 + lane) * 8);
        acc2[mf] = __builtin_amdgcn_mfma_f32_16x16x32_bf16(af, bfr, acc2[mf], 0, 0, 0);
      }
    }
    const int pos = pos_base + ps + lm;
    if (pos < HW) {
      float* boxOut = out + (size_t)8 * 18 * HW;
#pragma unroll
      for (int mf = 0; mf < 4; ++mf) {
#pragma unroll
        for (int pr = 0; pr < 2; ++pr) {
          const int row0 = mf * 16 + lg * 4 + pr * 2;
          const float v0 = acc2[mf][pr * 2];
          const float v1 = acc2[mf][pr * 2 + 1];
          if (row0 < 18) {
            const int a = row0 >> 1;
            const float s0 = v0 + clsb[a];
            const float s1 = v1 + clsb[9 + a];
            const float mx = fmaxf(s0, s1);
            const float e0 = expf(s0 - mx), e1 = expf(s1 - mx);
            const float inv = 1.0f / (e0 + e1);
            out[((size_t)(b * 18 + a)) * HW + pos] = e0 * inv;
            out[((size_t)(b * 18 + 9 + a)) * HW + pos] = e1 * inv;
          } else if (row0 < 54) {
            const int c0 = row0 - 18;
            boxOut[((size_t)(b * 36 + c0)) * HW + pos] = v0 + boxb[c0];
            boxOut[((size_t)(b * 36 + c0 + 1)) * HW + pos] = v1 + boxb[c0 + 1];
          }
        }
      }
    }
  }
}

extern "C" void kernel_launch(void* const* d_in, const int* in_sizes, int n_in,
                              void* d_out, int out_size, void* d_ws, size_t ws_size,
                              hipStream_t stream) {
  (void)in_sizes; (void)n_in; (void)out_size; (void)ws_size;
  const float* base_feat = (const float*)d_in[0];
  const float* conv_w = (const float*)d_in[4];
  const float* conv_b = (const float*)d_in[5];
  const float* cls_w  = (const float*)d_in[6];
  const float* cls_b  = (const float*)d_in[7];
  const float* bbox_w = (const float*)d_in[8];
  const float* bbox_b = (const float*)d_in[9];

  char* ws = (char*)d_ws;
  bf16_t* Xp   = (bf16_t*)(ws);                // 8*52*78*512*2 = 33,226,752 B
  bf16_t* Wt   = (bf16_t*)(ws + 33226752);     // 9*512*512*2   =  4,718,592 B
  bf16_t* WhbF = (bf16_t*)(ws + 37945344);     // 4*16*64*8*2   =     65,536 B

  hipLaunchKernelGGL(prep_all,   dim3(2144), dim3(256), 0, stream,
                     base_feat, conv_w, cls_w, bbox_w, Xp, Wt, WhbF);
  hipLaunchKernelGGL(conv_fused, dim3(240),  dim3(512), 0, stream,
                     Xp, Wt, conv_b, WhbF, cls_b, bbox_b, (float*)d_out);
}